// Round 1
// baseline (719.805 us; speedup 1.0000x reference)
//
#include <hip/hip_runtime.h>

// IntraClusterGAT on MI355X — Round 1: correct fp32, algebraically restructured.
//
// Key identities:
//   scores[s,t] = x_s^T M x_t,  M = W_Q^T W_K / sqrt(64)   (Q,K never materialized)
//   h[s] = W_V (attn[s,:] @ Xc) = W_V g[s]                  (V never materialized)
//   final = x + head_w * (W_out W_V) (accum_g / count) + b  (P = head_w*W_out@W_V)
//
// ws layout (floats): accum[200000*64] | count[200000] | Mstore[4096] | P[4096]
// ws bytes needed: ~52.1 MB.

#define NV 100000
#define NC 100000
#define NN 200000
#define D 64
#define S 128
#define NCLUST 2048
#define NEG_SLOPE 0.2f
#define GAMMA 1.0f
#define XS 68   // padded LDS row stride (floats): 16B-aligned, bank-even for b128/b32

__global__ __launch_bounds__(256) void prep_kernel(
    const float* __restrict__ WQ, const float* __restrict__ WK,
    const float* __restrict__ WV, const float* __restrict__ Wout,
    const float* __restrict__ head_weights, const int* __restrict__ active_heads_p,
    float* __restrict__ Mstore, float* __restrict__ P)
{
    int o = blockIdx.x * blockDim.x + threadIdx.x;   // 0..8191
    int ah = active_heads_p[0];
    float hw = 0.f;
    for (int i = 0; i < ah; ++i) hw += head_weights[i];
    hw /= (float)ah;
    if (o < 4096) {
        // Mstore[d][a] = M[a][d]/1 with scale folded: sum_j WQ[j][a]*WK[j][d] / 8
        int d = o >> 6, a = o & 63;
        float acc = 0.f;
        for (int j = 0; j < 64; ++j) acc += WQ[j*64 + a] * WK[j*64 + d];
        Mstore[o] = acc * 0.125f;
    } else if (o < 8192) {
        // P[j][b] = hw * sum_d Wout[j][d] * WV[d][b]
        int o2 = o - 4096;
        int j = o2 >> 6, b = o2 & 63;
        float acc = 0.f;
        for (int d = 0; d < 64; ++d) acc += Wout[j*64 + d] * WV[d*64 + b];
        P[o2] = acc * hw;
    }
}

__global__ __launch_bounds__(256) void attn_kernel(
    const float* __restrict__ x_var, const float* __restrict__ x_clause,
    const int* __restrict__ cvar, const int* __restrict__ ccl,
    const float* __restrict__ sat, const float* __restrict__ Mstore,
    float* __restrict__ accum, float* __restrict__ countv)
{
    __shared__ float Xc[S * XS];      // 34816 B  gathered node features
    __shared__ float Mt[64 * XS];     // 17408 B  M^T rows (lane d owns row d)
    __shared__ float zbuf[4 * 64];    // per-wave z vector
    __shared__ float attnbuf[4 * 128];// per-wave attn row
    __shared__ float biascl[64];      // gamma * sat for clause columns
    __shared__ int   ids[S];          // global node ids
    // total 56,064 B -> 2 blocks/CU

    const int tid  = threadIdx.x;
    const int c    = blockIdx.x;
    const int lane = tid & 63;
    const int w    = tid >> 6;

    // stage Mstore (64x64) into padded Mt
    for (int i = tid; i < 64 * 16; i += 256) {
        int r = i >> 4, c4 = i & 15;
        float4 v = ((const float4*)Mstore)[r * 16 + c4];
        *((float4*)&Mt[r * XS + c4 * 4]) = v;
    }

    // gather 128 rows, 2 threads per row (256B contiguous per row)
    {
        int r = tid >> 1, half = tid & 1;
        const float* src;
        if (r < 64) {
            int vid = cvar[c * 64 + r];
            src = x_var + (size_t)vid * D;
            if (!half) ids[r] = vid;
        } else {
            int cid = ccl[c * 64 + (r - 64)];
            src = x_clause + (size_t)cid * D;
            if (!half) ids[r] = NV + cid;
            if (half)  biascl[r - 64] = GAMMA * sat[cid];
        }
        const float4* s4 = (const float4*)src + half * 8;
        float4* d4 = (float4*)&Xc[r * XS + half * 32];
        #pragma unroll
        for (int i = 0; i < 8; ++i) d4[i] = s4[i];
    }
    __syncthreads();

    // each wave processes rows s = w, w+4, ...
    for (int s = w; s < S; s += 4) {
        // z[d] = sum_a Mt[d][a] * Xc[s][a]   (lane d)
        const float4* mrow = (const float4*)&Mt[lane * XS];
        const float4* xrow = (const float4*)&Xc[s * XS];
        float z0 = 0.f, z1 = 0.f, z2 = 0.f, z3 = 0.f;
        #pragma unroll
        for (int i = 0; i < 16; ++i) {
            float4 m = mrow[i], x = xrow[i];
            z0 += m.x * x.x; z1 += m.y * x.y; z2 += m.z * x.z; z3 += m.w * x.w;
        }
        zbuf[w * 64 + lane] = z0 + z1 + z2 + z3;
        // wave-local RAW on zbuf: same wave, lockstep, compiler orders via lgkmcnt

        // scores for t = lane and t = lane+64
        const float4* zr = (const float4*)&zbuf[w * 64];
        const float4* xa = (const float4*)&Xc[lane * XS];
        const float4* xb = (const float4*)&Xc[(lane + 64) * XS];
        float s0 = 0.f, s1 = 0.f;
        #pragma unroll
        for (int i = 0; i < 16; ++i) {
            float4 zz = zr[i], a0 = xa[i], a1 = xb[i];
            s0 += zz.x * a0.x + zz.y * a0.y + zz.z * a0.z + zz.w * a0.w;
            s1 += zz.x * a1.x + zz.y * a1.y + zz.z * a1.z + zz.w * a1.w;
        }
        s1 += biascl[lane];                       // bias only on clause columns
        s0 = s0 >= 0.f ? s0 : NEG_SLOPE * s0;     // leaky_relu
        s1 = s1 >= 0.f ? s1 : NEG_SLOPE * s1;

        // softmax over 128 (2 per lane)
        float mx = fmaxf(s0, s1);
        #pragma unroll
        for (int off = 32; off > 0; off >>= 1) mx = fmaxf(mx, __shfl_xor(mx, off, 64));
        float e0 = __expf(s0 - mx), e1 = __expf(s1 - mx);
        float sm = e0 + e1;
        #pragma unroll
        for (int off = 32; off > 0; off >>= 1) sm += __shfl_xor(sm, off, 64);
        float inv = 1.0f / sm;
        attnbuf[w * 128 + lane]      = e0 * inv;
        attnbuf[w * 128 + 64 + lane] = e1 * inv;

        // g[d] = sum_t attn[t] * Xc[t][d]   (lane d); attn via uniform b128 reads
        float g = 0.f;
        const float4* ar4 = (const float4*)&attnbuf[w * 128];
        #pragma unroll 8
        for (int i = 0; i < 32; ++i) {
            float4 a4 = ar4[i];
            int t = i * 4;
            g += a4.x * Xc[t * XS + lane]
               + a4.y * Xc[(t + 1) * XS + lane]
               + a4.z * Xc[(t + 2) * XS + lane]
               + a4.w * Xc[(t + 3) * XS + lane];
        }

        int nid = ids[s];
        atomicAdd(&accum[(size_t)nid * D + lane], g);
        if (lane == 0) atomicAdd(&countv[nid], 1.0f);
    }
}

__global__ __launch_bounds__(256) void finalize_kernel(
    const float* __restrict__ x_var, const float* __restrict__ x_clause,
    const float* __restrict__ accum, const float* __restrict__ countv,
    const float* __restrict__ P, const float* __restrict__ bout,
    float* __restrict__ out)
{
    __shared__ float grow[4 * 64];
    const int tid = threadIdx.x, lane = tid & 63, w = tid >> 6;

    // P row j=lane into registers (one-time, cached)
    float preg[64];
    #pragma unroll
    for (int i = 0; i < 16; ++i) {
        float4 v = ((const float4*)P)[lane * 16 + i];
        preg[4*i] = v.x; preg[4*i+1] = v.y; preg[4*i+2] = v.z; preg[4*i+3] = v.w;
    }
    float bj = bout[lane];

    int gw = blockIdx.x * 4 + w;
    int nw = gridDim.x * 4;
    for (int n = gw; n < NN; n += nw) {
        float av = accum[(size_t)n * D + lane];
        grow[w * 64 + lane] = av;
        float cnt = countv[n];
        float inv = 1.0f / fmaxf(cnt, 1.0f);
        // dot = P[lane][:] . accum_row
        float dot = 0.f;
        const float4* gr4 = (const float4*)&grow[w * 64];
        #pragma unroll
        for (int i = 0; i < 16; ++i) {
            float4 g4 = gr4[i];
            dot += preg[4*i] * g4.x + preg[4*i+1] * g4.y
                 + preg[4*i+2] * g4.z + preg[4*i+3] * g4.w;
        }
        float xv = (n < NV) ? x_var[(size_t)n * D + lane]
                            : x_clause[(size_t)(n - NV) * D + lane];
        out[(size_t)n * D + lane] = xv + dot * inv + bj;
    }
}

extern "C" void kernel_launch(void* const* d_in, const int* in_sizes, int n_in,
                              void* d_out, int out_size, void* d_ws, size_t ws_size,
                              hipStream_t stream)
{
    const float* x_var        = (const float*)d_in[0];
    const float* x_clause     = (const float*)d_in[1];
    // d_in[2] var_clause_edge_index, d_in[3] edge_polarity: unused by reference
    const int*   cvar         = (const int*)d_in[4];
    const int*   ccl          = (const int*)d_in[5];
    const float* sat          = (const float*)d_in[6];
    const int*   active_heads = (const int*)d_in[7];
    const float* WQ           = (const float*)d_in[8];
    const float* WK           = (const float*)d_in[9];
    const float* WV           = (const float*)d_in[10];
    const float* head_weights = (const float*)d_in[11];
    const float* Wout         = (const float*)d_in[12];
    const float* bout         = (const float*)d_in[13];

    float* ws     = (float*)d_ws;
    float* accum  = ws;                              // 200000*64
    float* countv = ws + (size_t)NN * D;             // 200000
    float* Mstore = countv + NN;                     // 4096
    float* P      = Mstore + 4096;                   // 4096

    hipMemsetAsync(accum, 0, (size_t)(NN * D + NN) * sizeof(float), stream);
    prep_kernel<<<32, 256, 0, stream>>>(WQ, WK, WV, Wout, head_weights, active_heads, Mstore, P);
    attn_kernel<<<NCLUST, 256, 0, stream>>>(x_var, x_clause, cvar, ccl, sat, Mstore, accum, countv);
    finalize_kernel<<<2048, 256, 0, stream>>>(x_var, x_clause, accum, countv, P, bout, (float*)d_out);
}

// Round 2
// 285.744 us; speedup vs baseline: 2.5191x; 2.5191x over previous
//
#include <hip/hip_runtime.h>

// IntraClusterGAT on MI355X — Round 2: bf16 MFMA (32x32x16) for all three
// per-cluster GEMMs + MFMA finalize.
//
//   Zc = Xc@M (K=64) ; scores = Zc@Xc^T (K=64) ; softmax fp32 ; g = attn@Xc (K=128)
//   scatter g with fp32 atomics ; finalize: out = x + (accum/count)@P^T + b  (MFMA)
//
// Wave w owns m-tile w (rows 32w..32w+31) in every phase -> Zc/attn handoffs are
// wave-local (no barrier). attn aliases dead Mt+Zc region: 71KB LDS -> 2 blocks/CU.

#define NV 100000
#define NN 200000
#define NCLUST 2048
#define XS 72    // Xc/Zc/Mt/G row stride in bf16 elems (144B, 16B-aligned)
#define AS 136   // attn/XcT row stride (272B, 16B-aligned)

typedef __attribute__((ext_vector_type(8))) short short8;
typedef __attribute__((ext_vector_type(16))) float floatx16;

__device__ __forceinline__ unsigned short f2bf(float f) {
    union { float f; unsigned u; } v; v.f = f;
    unsigned r = v.u + 0x7fffu + ((v.u >> 16) & 1u);   // RNE
    return (unsigned short)(r >> 16);
}

__global__ __launch_bounds__(256) void prep_kernel(
    const float* __restrict__ WQ, const float* __restrict__ WK,
    const float* __restrict__ WV, const float* __restrict__ Wout,
    const float* __restrict__ head_weights, const int* __restrict__ active_heads_p,
    unsigned short* __restrict__ Mtr, unsigned short* __restrict__ Pbf)
{
    int o = blockIdx.x * blockDim.x + threadIdx.x;   // 0..8191
    int ah = active_heads_p[0];
    float hw = 0.f;
    for (int i = 0; i < ah; ++i) hw += head_weights[i];
    hw /= (float)ah;
    if (o < 4096) {
        // Mtr[d][a] = M[a][d],  M = WQ^T WK / 8
        int d = o >> 6, a = o & 63;
        float acc = 0.f;
        for (int j = 0; j < 64; ++j) acc += WQ[j*64 + a] * WK[j*64 + d];
        Mtr[o] = f2bf(acc * 0.125f);
    } else if (o < 8192) {
        // Pbf[j][b] = hw * sum_d Wout[j][d] WV[d][b]
        int o2 = o - 4096;
        int j = o2 >> 6, b = o2 & 63;
        float acc = 0.f;
        for (int d = 0; d < 64; ++d) acc += Wout[j*64 + d] * WV[d*64 + b];
        Pbf[o2] = f2bf(acc * hw);
    }
}

__global__ __launch_bounds__(256, 2) void attn_kernel(
    const float* __restrict__ x_var, const float* __restrict__ x_clause,
    const int* __restrict__ cvar, const int* __restrict__ ccl,
    const float* __restrict__ sat, const unsigned short* __restrict__ Mtr,
    float* __restrict__ accum, float* __restrict__ countv)
{
    __shared__ unsigned short Xc[128 * XS];       // 18432 B  row-major bf16
    __shared__ unsigned short XcT[64 * AS];       // 17408 B  transposed bf16
    __shared__ union {
        struct { unsigned short Mt[64 * XS]; unsigned short Zc[128 * XS]; } s;
        unsigned short attn[128 * AS];            // 34816 B (aliases Mt+Zc, both dead)
    } u;
    __shared__ float biascl[64];
    __shared__ int ids[128];
    // total ~71.5 KB -> 2 blocks/CU

    const int tid = threadIdx.x;
    const int lane = tid & 63;
    const int w = tid >> 6;
    const int c = blockIdx.x;

    // stage M^T (bf16 4096) into padded rows
    for (int i = tid; i < 512; i += 256) {
        int r = i >> 3, q = i & 7;
        *(short8*)&u.s.Mt[r * XS + q * 8] = *(const short8*)(Mtr + r * 64 + q * 8);
    }

    // gather 128 node rows (2 threads/row, 32 floats each), cvt bf16,
    // write both Xc (row-major) and XcT (scatter)
    {
        const int r = tid >> 1, half = tid & 1;
        const float* src; int nid;
        if (r < 64) {
            int vid = cvar[c * 64 + r]; nid = vid;
            src = x_var + (size_t)vid * 64;
        } else {
            int cid = ccl[c * 64 + (r - 64)]; nid = NV + cid;
            src = x_clause + (size_t)cid * 64;
            if (half) biascl[r - 64] = sat[cid];       // GAMMA = 1
        }
        if (!half) ids[r] = nid;
        union { unsigned short us[32]; short8 v[4]; } hb;
        const float4* s4 = (const float4*)src + half * 8;
        #pragma unroll
        for (int i = 0; i < 8; ++i) {
            float4 v = s4[i];
            hb.us[i*4+0] = f2bf(v.x); hb.us[i*4+1] = f2bf(v.y);
            hb.us[i*4+2] = f2bf(v.z); hb.us[i*4+3] = f2bf(v.w);
        }
        const int c0 = half * 32;
        #pragma unroll
        for (int i = 0; i < 4; ++i) *(short8*)&Xc[r * XS + c0 + i * 8] = hb.v[i];
        #pragma unroll
        for (int i = 0; i < 32; ++i) XcT[(c0 + i) * AS + r] = hb.us[i];
    }
    __syncthreads();
    if (tid < 128) atomicAdd(&countv[ids[tid]], 1.0f);

    const int m = lane & 31;             // m/n index within 32-tile
    const int hk = (lane >> 5) * 8;      // k-offset within 16-step

    // ---- GEMM1: Zc = Xc @ M   (wave w: m-tile w, n-tiles 0..1, K=64) ----
    floatx16 z0 = {}, z1 = {};
    #pragma unroll
    for (int ks = 0; ks < 4; ++ks) {
        short8 a  = *(const short8*)&Xc[(w * 32 + m) * XS + ks * 16 + hk];
        short8 b0 = *(const short8*)&u.s.Mt[m * XS + ks * 16 + hk];
        short8 b1 = *(const short8*)&u.s.Mt[(32 + m) * XS + ks * 16 + hk];
        z0 = __builtin_amdgcn_mfma_f32_32x32x16_bf16(a, b0, z0, 0, 0, 0);
        z1 = __builtin_amdgcn_mfma_f32_32x32x16_bf16(a, b1, z1, 0, 0, 0);
    }
    #pragma unroll
    for (int r = 0; r < 16; ++r) {   // C layout: col=lane&31, row=(r&3)+8*(r>>2)+4*(lane>>5)
        int row = w * 32 + (r & 3) + 8 * (r >> 2) + 4 * (lane >> 5);
        u.s.Zc[row * XS + m]      = f2bf(z0[r]);
        u.s.Zc[row * XS + 32 + m] = f2bf(z1[r]);
    }
    // wave-local RAW (same wave reads its own Zc rows) — no barrier needed

    // ---- GEMM2: scores = Zc @ Xc^T  (m-tile w, n-tiles 0..3, K=64) ----
    floatx16 sc[4] = {{}, {}, {}, {}};
    #pragma unroll
    for (int ks = 0; ks < 4; ++ks) {
        short8 a = *(const short8*)&u.s.Zc[(w * 32 + m) * XS + ks * 16 + hk];
        #pragma unroll
        for (int nt = 0; nt < 4; ++nt) {
            short8 b = *(const short8*)&Xc[(nt * 32 + m) * XS + ks * 16 + hk];
            sc[nt] = __builtin_amdgcn_mfma_f32_32x32x16_bf16(a, b, sc[nt], 0, 0, 0);
        }
    }

    // ---- bias + leaky_relu + softmax (fp32, row-wise over 128 cols) ----
    const float b2 = biascl[m], b3 = biascl[32 + m];
    #pragma unroll
    for (int r = 0; r < 16; ++r) {
        float a0 = sc[0][r], a1 = sc[1][r], a2 = sc[2][r] + b2, a3 = sc[3][r] + b3;
        a0 = a0 > 0.f ? a0 : 0.2f * a0;
        a1 = a1 > 0.f ? a1 : 0.2f * a1;
        a2 = a2 > 0.f ? a2 : 0.2f * a2;
        a3 = a3 > 0.f ? a3 : 0.2f * a3;
        float mx = fmaxf(fmaxf(a0, a1), fmaxf(a2, a3));
        #pragma unroll
        for (int off = 1; off < 32; off <<= 1) mx = fmaxf(mx, __shfl_xor(mx, off, 64));
        a0 = __expf(a0 - mx); a1 = __expf(a1 - mx);
        a2 = __expf(a2 - mx); a3 = __expf(a3 - mx);
        float sm = a0 + a1 + a2 + a3;
        #pragma unroll
        for (int off = 1; off < 32; off <<= 1) sm += __shfl_xor(sm, off, 64);
        float inv = 1.0f / sm;
        sc[0][r] = a0 * inv; sc[1][r] = a1 * inv;
        sc[2][r] = a2 * inv; sc[3][r] = a3 * inv;
    }

    __syncthreads();   // all waves done reading Zc/Xc before attn overwrites Mt+Zc

    #pragma unroll
    for (int r = 0; r < 16; ++r) {
        int row = w * 32 + (r & 3) + 8 * (r >> 2) + 4 * (lane >> 5);
        u.attn[row * AS + m]      = f2bf(sc[0][r]);
        u.attn[row * AS + 32 + m] = f2bf(sc[1][r]);
        u.attn[row * AS + 64 + m] = f2bf(sc[2][r]);
        u.attn[row * AS + 96 + m] = f2bf(sc[3][r]);
    }

    // ---- GEMM3: g = attn @ Xc  (m-tile w, n-tiles 0..1, K=128) ----
    floatx16 g0 = {}, g1 = {};
    #pragma unroll
    for (int ks = 0; ks < 8; ++ks) {
        short8 a  = *(const short8*)&u.attn[(w * 32 + m) * AS + ks * 16 + hk];
        short8 b0 = *(const short8*)&XcT[m * AS + ks * 16 + hk];
        short8 b1 = *(const short8*)&XcT[(32 + m) * AS + ks * 16 + hk];
        g0 = __builtin_amdgcn_mfma_f32_32x32x16_bf16(a, b0, g0, 0, 0, 0);
        g1 = __builtin_amdgcn_mfma_f32_32x32x16_bf16(a, b1, g1, 0, 0, 0);
    }

    // ---- scatter-add g rows to accum ----
    #pragma unroll
    for (int r = 0; r < 16; ++r) {
        int row = w * 32 + (r & 3) + 8 * (r >> 2) + 4 * (lane >> 5);
        float* base = accum + (size_t)ids[row] * 64;
        atomicAdd(base + m,      g0[r]);
        atomicAdd(base + 32 + m, g1[r]);
    }
}

__global__ __launch_bounds__(256, 3) void finalize_kernel(
    const float* __restrict__ x_var, const float* __restrict__ x_clause,
    const float* __restrict__ accum, const float* __restrict__ countv,
    const unsigned short* __restrict__ Pbf, const float* __restrict__ bout,
    float* __restrict__ out)
{
    __shared__ unsigned short G[256 * XS];   // 36864 B  (accum/count) in bf16
    __shared__ unsigned short Pl[64 * XS];   //  9216 B
    const int tid = threadIdx.x, lane = tid & 63, w = tid >> 6;
    const int base = blockIdx.x * 256;

    for (int i = tid; i < 512; i += 256) {
        int r = i >> 3, q = i & 7;
        *(short8*)&Pl[r * XS + q * 8] = *(const short8*)(Pbf + r * 64 + q * 8);
    }
    // stage Gdiv = accum/max(count,1) as bf16 (fully coalesced float2 loads)
    #pragma unroll 4
    for (int it = 0; it < 32; ++it) {
        int idx2 = it * 256 + tid;           // float2 index in block (0..8191)
        int lrow = idx2 >> 5;                // 0..255
        int col2 = idx2 & 31;
        int n = base + lrow;
        float2 v = make_float2(0.f, 0.f);
        float cnt = 1.f;
        if (n < NN) {
            v = *(const float2*)(accum + (size_t)n * 64 + col2 * 2);
            cnt = countv[n];
        }
        float inv = 1.0f / fmaxf(cnt, 1.0f);
        unsigned pk = (unsigned)f2bf(v.x * inv) | ((unsigned)f2bf(v.y * inv) << 16);
        *(unsigned*)&G[lrow * XS + col2 * 2] = pk;
    }
    __syncthreads();

    const int m = lane & 31, hk = (lane >> 5) * 8;
    short8 pb[2][4];
    #pragma unroll
    for (int nt = 0; nt < 2; ++nt)
        #pragma unroll
        for (int ks = 0; ks < 4; ++ks)
            pb[nt][ks] = *(const short8*)&Pl[(nt * 32 + m) * XS + ks * 16 + hk];
    const float bias0 = bout[m], bias1 = bout[32 + m];

    #pragma unroll
    for (int tm = 0; tm < 2; ++tm) {
        int mt = w * 2 + tm;                 // m-tile 0..7 (rows mt*32..)
        floatx16 c0 = {}, c1 = {};
        #pragma unroll
        for (int ks = 0; ks < 4; ++ks) {
            short8 a = *(const short8*)&G[(mt * 32 + m) * XS + ks * 16 + hk];
            c0 = __builtin_amdgcn_mfma_f32_32x32x16_bf16(a, pb[0][ks], c0, 0, 0, 0);
            c1 = __builtin_amdgcn_mfma_f32_32x32x16_bf16(a, pb[1][ks], c1, 0, 0, 0);
        }
        #pragma unroll
        for (int r = 0; r < 16; ++r) {
            int lrow = mt * 32 + (r & 3) + 8 * (r >> 2) + 4 * (lane >> 5);
            int n = base + lrow;
            if (n < NN) {
                const float* xs = (n < NV) ? (x_var + (size_t)n * 64)
                                           : (x_clause + (size_t)(n - NV) * 64);
                out[(size_t)n * 64 + m]      = xs[m]      + c0[r] + bias0;
                out[(size_t)n * 64 + 32 + m] = xs[32 + m] + c1[r] + bias1;
            }
        }
    }
}

extern "C" void kernel_launch(void* const* d_in, const int* in_sizes, int n_in,
                              void* d_out, int out_size, void* d_ws, size_t ws_size,
                              hipStream_t stream)
{
    const float* x_var        = (const float*)d_in[0];
    const float* x_clause     = (const float*)d_in[1];
    const int*   cvar         = (const int*)d_in[4];
    const int*   ccl          = (const int*)d_in[5];
    const float* sat          = (const float*)d_in[6];
    const int*   active_heads = (const int*)d_in[7];
    const float* WQ           = (const float*)d_in[8];
    const float* WK           = (const float*)d_in[9];
    const float* WV           = (const float*)d_in[10];
    const float* head_weights = (const float*)d_in[11];
    const float* Wout         = (const float*)d_in[12];
    const float* bout         = (const float*)d_in[13];

    float* accum  = (float*)d_ws;                        // NN*64
    float* countv = accum + (size_t)NN * 64;             // NN
    unsigned short* Mtr = (unsigned short*)(countv + NN); // 4096 bf16
    unsigned short* Pbf = Mtr + 4096;                     // 4096 bf16

    hipMemsetAsync(accum, 0, (size_t)(NN * 64 + NN) * sizeof(float), stream);
    prep_kernel<<<32, 256, 0, stream>>>(WQ, WK, WV, Wout, head_weights, active_heads, Mtr, Pbf);
    attn_kernel<<<NCLUST, 256, 0, stream>>>(x_var, x_clause, cvar, ccl, sat, Mtr, accum, countv);
    finalize_kernel<<<(NN + 255) / 256, 256, 0, stream>>>(x_var, x_clause, accum, countv, Pbf, bout, (float*)d_out);
}

// Round 4
// 252.907 us; speedup vs baseline: 2.8461x; 1.1298x over previous
//
#include <hip/hip_runtime.h>

// IntraClusterGAT on MI355X — Round 4.
// Self-contained attn kernel (NO global staging — d_out is written only by
// finalize; round-3's d_out-as-scratch broke the post-timing tripwire).
//
//   prep:  Mtr = (WQ^T WK/8)^T, Pbf = hw*Wout@WV (bf16, in ws)
//   attn:  gather fp32->bf16 Xc/XcT -> Zc=Xc@M (MFMA, M frags from global/L1)
//          -> scores=Zc@Xc^T (MFMA) -> exp (no max-sub) -> attn (bf16, aliases
//          Zc+Xc) -> g=E@Xc + rowsum=E@ones (MFMA) -> rcp-normalize -> atomic
//          scatter to accum
//   final: out = x + (accum/count)@P^T + b  (MFMA, P frags from global/L1)
//
// attn LDS = 54272B -> 3 blocks/CU; finalize 36864B -> 4 blocks/CU.

#define NV 100000
#define NN 200000
#define NCLUST 2048
#define XS 72    // Zc/Xc/G row stride (bf16): 144B, 16B-aligned
#define AS 136   // attn/XcT row stride (bf16): 272B, 16B-aligned

typedef __attribute__((ext_vector_type(8))) short short8;
typedef __attribute__((ext_vector_type(16))) float floatx16;

__device__ __forceinline__ unsigned short f2bf(float f) {
    union { float f; unsigned u; } v; v.f = f;
    unsigned r = v.u + 0x7fffu + ((v.u >> 16) & 1u);   // RNE
    return (unsigned short)(r >> 16);
}
__device__ __forceinline__ int crow(int r, int lane) {   // MFMA 32x32 C row map
    return (r & 3) + 8 * (r >> 2) + 4 * (lane >> 5);
}

__global__ __launch_bounds__(256) void prep_kernel(
    const float* __restrict__ WQ, const float* __restrict__ WK,
    const float* __restrict__ WV, const float* __restrict__ Wout,
    const float* __restrict__ head_weights, const int* __restrict__ active_heads_p,
    unsigned short* __restrict__ Mtr, unsigned short* __restrict__ Pbf)
{
    int o = blockIdx.x * blockDim.x + threadIdx.x;
    int ah = active_heads_p[0];
    float hw = 0.f;
    for (int i = 0; i < ah; ++i) hw += head_weights[i];
    hw /= (float)ah;
    if (o < 4096) {
        int d = o >> 6, a = o & 63;                       // Mtr[d][a] = M[a][d]
        float acc = 0.f;
        for (int j = 0; j < 64; ++j) acc += WQ[j*64 + a] * WK[j*64 + d];
        Mtr[o] = f2bf(acc * 0.125f);
    } else if (o < 8192) {
        int o2 = o - 4096;
        int j = o2 >> 6, b = o2 & 63;                     // Pbf[j][b]
        float acc = 0.f;
        for (int d = 0; d < 64; ++d) acc += Wout[j*64 + d] * WV[d*64 + b];
        Pbf[o2] = f2bf(acc * hw);
    }
}

__global__ __launch_bounds__(256, 3) void attn_kernel(
    const float* __restrict__ x_var, const float* __restrict__ x_clause,
    const int* __restrict__ cvar, const int* __restrict__ ccl,
    const float* __restrict__ sat, const unsigned short* __restrict__ Mtr,
    float* __restrict__ accum, float* __restrict__ countv)
{
    __shared__ union {
        struct { unsigned short Zc[128 * XS]; unsigned short Xc[128 * XS]; } s; // 36864
        unsigned short attn[128 * AS];                                          // 34816
    } u;
    __shared__ unsigned short XcT[64 * AS];   // 17408; row pads hold ids(8B)+bias(4B)
    // total 54272 B -> 3 blocks/CU

    const int tid = threadIdx.x, lane = tid & 63, w = tid >> 6;
    const int c = blockIdx.x;
    const int m = lane & 31, hk = (lane >> 5) * 8;

    // M fragments straight from global (L1-resident, identical for all blocks)
    short8 mb0[4], mb1[4];
    #pragma unroll
    for (int ks = 0; ks < 4; ++ks) {
        mb0[ks] = *(const short8*)(Mtr + m * 64 + ks * 16 + hk);
        mb1[ks] = *(const short8*)(Mtr + (32 + m) * 64 + ks * 16 + hk);
    }

    // ---- gather: fp32 rows -> bf16 -> Xc (row-major) + XcT (transposed) ----
    {
        const int r = tid >> 1, half = tid & 1;
        int nid;
        const float* src;
        if (r < 64) {
            nid = cvar[c * 64 + r];
            src = x_var + (size_t)nid * 64;
        } else {
            int cid = ccl[c * 64 + (r - 64)];
            nid = NV + cid;
            src = x_clause + (size_t)cid * 64;
            if (half) *(float*)&XcT[(r - 64) * AS + 132] = sat[cid];  // GAMMA=1
        }
        if (!half) ((int*)&XcT[(r >> 1) * AS + 128])[r & 1] = nid;
        union { unsigned short us[32]; short8 v[4]; } hb;
        const float4* s4 = (const float4*)src + half * 8;
        #pragma unroll
        for (int i = 0; i < 8; ++i) {
            float4 v = s4[i];
            hb.us[i*4+0] = f2bf(v.x); hb.us[i*4+1] = f2bf(v.y);
            hb.us[i*4+2] = f2bf(v.z); hb.us[i*4+3] = f2bf(v.w);
        }
        const int c0 = half * 32;
        #pragma unroll
        for (int i = 0; i < 4; ++i) *(short8*)&u.s.Xc[r * XS + c0 + i * 8] = hb.v[i];
        #pragma unroll
        for (int i = 0; i < 32; ++i) XcT[(c0 + i) * AS + r] = hb.us[i];
    }
    __syncthreads();
    if (tid < 128)
        atomicAdd(&countv[((const int*)&XcT[(tid >> 1) * AS + 128])[tid & 1]], 1.0f);

    // ---- GEMM1: Zc = Xc @ M  (m-tile w, K=64; B from global regs) ----
    floatx16 z0 = {}, z1 = {};
    #pragma unroll
    for (int ks = 0; ks < 4; ++ks) {
        short8 a = *(const short8*)&u.s.Xc[(w * 32 + m) * XS + ks * 16 + hk];
        z0 = __builtin_amdgcn_mfma_f32_32x32x16_bf16(a, mb0[ks], z0, 0, 0, 0);
        z1 = __builtin_amdgcn_mfma_f32_32x32x16_bf16(a, mb1[ks], z1, 0, 0, 0);
    }
    #pragma unroll
    for (int r = 0; r < 16; ++r) {     // wave-local rows 32w..32w+31
        int row = w * 32 + crow(r, lane);
        u.s.Zc[row * XS + m]      = f2bf(z0[r]);
        u.s.Zc[row * XS + 32 + m] = f2bf(z1[r]);
    }

    // ---- GEMM2: scores = Zc @ Xc^T  (m-tile w, n-tiles 0..3, K=64) ----
    floatx16 sc[4] = {{}, {}, {}, {}};
    #pragma unroll
    for (int ks = 0; ks < 4; ++ks) {
        short8 a = *(const short8*)&u.s.Zc[(w * 32 + m) * XS + ks * 16 + hk];
        #pragma unroll
        for (int nt = 0; nt < 4; ++nt) {
            short8 b = *(const short8*)&u.s.Xc[(nt * 32 + m) * XS + ks * 16 + hk];
            sc[nt] = __builtin_amdgcn_mfma_f32_32x32x16_bf16(a, b, sc[nt], 0, 0, 0);
        }
    }

    // ---- bias + leaky_relu + exp (no max-sub: |score| <~ 8 << 88) ----
    const float b2 = *(const float*)&XcT[m * AS + 132];
    const float b3 = *(const float*)&XcT[(32 + m) * AS + 132];
    #pragma unroll
    for (int r = 0; r < 16; ++r) {
        float a0 = sc[0][r], a1 = sc[1][r], a2 = sc[2][r] + b2, a3 = sc[3][r] + b3;
        a0 = a0 > 0.f ? a0 : 0.2f * a0;
        a1 = a1 > 0.f ? a1 : 0.2f * a1;
        a2 = a2 > 0.f ? a2 : 0.2f * a2;
        a3 = a3 > 0.f ? a3 : 0.2f * a3;
        sc[0][r] = __expf(a0); sc[1][r] = __expf(a1);
        sc[2][r] = __expf(a2); sc[3][r] = __expf(a3);
    }

    __syncthreads();   // all waves done reading Zc/Xc before attn aliases them

    #pragma unroll
    for (int r = 0; r < 16; ++r) {
        int row = w * 32 + crow(r, lane);
        u.attn[row * AS + m]      = f2bf(sc[0][r]);
        u.attn[row * AS + 32 + m] = f2bf(sc[1][r]);
        u.attn[row * AS + 64 + m] = f2bf(sc[2][r]);
        u.attn[row * AS + 96 + m] = f2bf(sc[3][r]);
    }

    // ---- GEMM3: g = E@Xc (n-tiles 0..1) + rowsum = E@ones, K=128 ----
    const short8 vones = (short8)(short)0x3F80;   // bf16 1.0 splat
    floatx16 g0 = {}, g1 = {}, rs = {};
    #pragma unroll
    for (int ks = 0; ks < 8; ++ks) {
        short8 a  = *(const short8*)&u.attn[(w * 32 + m) * AS + ks * 16 + hk];
        short8 b0 = *(const short8*)&XcT[m * AS + ks * 16 + hk];
        short8 b1 = *(const short8*)&XcT[(32 + m) * AS + ks * 16 + hk];
        g0 = __builtin_amdgcn_mfma_f32_32x32x16_bf16(a, b0, g0, 0, 0, 0);
        g1 = __builtin_amdgcn_mfma_f32_32x32x16_bf16(a, b1, g1, 0, 0, 0);
        rs = __builtin_amdgcn_mfma_f32_32x32x16_bf16(a, vones, rs, 0, 0, 0);
    }

    // ---- normalize by rowsum + atomic scatter ----
    #pragma unroll
    for (int r = 0; r < 16; ++r) {
        int row = w * 32 + crow(r, lane);
        int nid = ((const int*)&XcT[(row >> 1) * AS + 128])[row & 1];
        float inv = __builtin_amdgcn_rcpf(rs[r]);
        float* base = accum + (size_t)nid * 64;
        atomicAdd(base + m,      g0[r] * inv);
        atomicAdd(base + 32 + m, g1[r] * inv);
    }
}

__global__ __launch_bounds__(256, 4) void finalize_kernel(
    const float* __restrict__ x_var, const float* __restrict__ x_clause,
    const float* __restrict__ accum, const float* __restrict__ countv,
    const unsigned short* __restrict__ Pbf, const float* __restrict__ bout,
    float* __restrict__ out)
{
    __shared__ unsigned short G[256 * XS];   // 36864 B -> 4 blocks/CU
    const int tid = threadIdx.x, lane = tid & 63, w = tid >> 6;
    const int base = blockIdx.x * 256;

    #pragma unroll 4
    for (int it = 0; it < 32; ++it) {
        int idx2 = it * 256 + tid;
        int lrow = idx2 >> 5, col2 = idx2 & 31;
        int n = base + lrow;
        float2 v = make_float2(0.f, 0.f);
        float cnt = 1.f;
        if (n < NN) {
            v = *(const float2*)(accum + (size_t)n * 64 + col2 * 2);
            cnt = countv[n];
        }
        float inv = 1.0f / fmaxf(cnt, 1.0f);
        unsigned pk = (unsigned)f2bf(v.x * inv) | ((unsigned)f2bf(v.y * inv) << 16);
        *(unsigned*)&G[lrow * XS + col2 * 2] = pk;
    }
    __syncthreads();

    const int m = lane & 31, hk = (lane >> 5) * 8;
    short8 pb[2][4];                              // P fragments via L1
    #pragma unroll
    for (int nt = 0; nt < 2; ++nt)
        #pragma unroll
        for (int ks = 0; ks < 4; ++ks)
            pb[nt][ks] = *(const short8*)(Pbf + (nt * 32 + m) * 64 + ks * 16 + hk);
    const float bias0 = bout[m], bias1 = bout[32 + m];

    #pragma unroll
    for (int tm = 0; tm < 2; ++tm) {
        int mt = w * 2 + tm;
        floatx16 c0 = {}, c1 = {};
        #pragma unroll
        for (int ks = 0; ks < 4; ++ks) {
            short8 a = *(const short8*)&G[(mt * 32 + m) * XS + ks * 16 + hk];
            c0 = __builtin_amdgcn_mfma_f32_32x32x16_bf16(a, pb[0][ks], c0, 0, 0, 0);
            c1 = __builtin_amdgcn_mfma_f32_32x32x16_bf16(a, pb[1][ks], c1, 0, 0, 0);
        }
        #pragma unroll
        for (int r = 0; r < 16; ++r) {
            int n = base + mt * 32 + crow(r, lane);
            if (n < NN) {
                const float* xs = (n < NV) ? (x_var + (size_t)n * 64)
                                           : (x_clause + (size_t)(n - NV) * 64);
                out[(size_t)n * 64 + m]      = xs[m]      + c0[r] + bias0;
                out[(size_t)n * 64 + 32 + m] = xs[32 + m] + c1[r] + bias1;
            }
        }
    }
}

extern "C" void kernel_launch(void* const* d_in, const int* in_sizes, int n_in,
                              void* d_out, int out_size, void* d_ws, size_t ws_size,
                              hipStream_t stream)
{
    const float* x_var        = (const float*)d_in[0];
    const float* x_clause     = (const float*)d_in[1];
    const int*   cvar         = (const int*)d_in[4];
    const int*   ccl          = (const int*)d_in[5];
    const float* sat          = (const float*)d_in[6];
    const int*   active_heads = (const int*)d_in[7];
    const float* WQ           = (const float*)d_in[8];
    const float* WK           = (const float*)d_in[9];
    const float* WV           = (const float*)d_in[10];
    const float* head_weights = (const float*)d_in[11];
    const float* Wout         = (const float*)d_in[12];
    const float* bout         = (const float*)d_in[13];

    float* accum  = (float*)d_ws;                          // NN*64 f32
    float* countv = accum + (size_t)NN * 64;               // NN f32
    unsigned short* Mtr = (unsigned short*)(countv + NN);  // 4096 bf16
    unsigned short* Pbf = Mtr + 4096;                      // 4096 bf16

    hipMemsetAsync(accum, 0, (size_t)(NN * 64 + NN) * sizeof(float), stream);
    prep_kernel<<<32, 256, 0, stream>>>(WQ, WK, WV, Wout, head_weights, active_heads, Mtr, Pbf);
    attn_kernel<<<NCLUST, 256, 0, stream>>>(x_var, x_clause, cvar, ccl, sat, Mtr, accum, countv);
    finalize_kernel<<<(NN + 255) / 256, 256, 0, stream>>>(x_var, x_clause, accum, countv, Pbf, bout, (float*)d_out);
}

// Round 5
// 214.637 us; speedup vs baseline: 3.3536x; 1.1783x over previous
//
#include <hip/hip_runtime.h>

// IntraClusterGAT on MI355X — Round 5.
//   prep:  Mtr = (WQ^T WK/8)^T, Pbf = hw*Wout@WV (bf16, in ws)
//   attn:  gather fp32->bf16 Xc/XcT -> Zc=Xc@M (MFMA) -> scores=Zc@Xc^T (MFMA)
//          -> exp (no max-sub) -> attn bf16 (aliases Zc+Xc) -> g=E@Xc +
//          rowsum=E@ones (MFMA) -> rcp-normalize -> pk_add_bf16 atomic scatter
//          (adjacent cols paired via shfl_xor(1): 1 dword atomic per lane)
//   final: out = x + (accum@P^T)/max(cnt,1) + b  — divide commutes with GEMM,
//          so A-frags stream straight from global bf16 accum (no LDS staging).
//
// ws: accum_bf[NN*64] bf16 | countv[NN] f32 | Mtr 4096 bf16 | Pbf 4096 bf16 (~26.4MB)

#define NV 100000
#define NN 200000
#define NCLUST 2048
#define XS 72    // Zc/Xc row stride (bf16): 144B, 16B-aligned
#define AS 136   // attn/XcT row stride (bf16): 272B, 16B-aligned

typedef __attribute__((ext_vector_type(8))) short short8;
typedef __attribute__((ext_vector_type(16))) float floatx16;

__device__ __forceinline__ unsigned short f2bf(float f) {
    union { float f; unsigned u; } v; v.f = f;
    unsigned r = v.u + 0x7fffu + ((v.u >> 16) & 1u);   // RNE
    return (unsigned short)(r >> 16);
}
__device__ __forceinline__ int crow(int r, int lane) {   // MFMA 32x32 C row map
    return (r & 3) + 8 * (r >> 2) + 4 * (lane >> 5);
}

__global__ __launch_bounds__(256) void prep_kernel(
    const float* __restrict__ WQ, const float* __restrict__ WK,
    const float* __restrict__ WV, const float* __restrict__ Wout,
    const float* __restrict__ head_weights, const int* __restrict__ active_heads_p,
    unsigned short* __restrict__ Mtr, unsigned short* __restrict__ Pbf)
{
    int o = blockIdx.x * blockDim.x + threadIdx.x;
    int ah = active_heads_p[0];
    float hw = 0.f;
    for (int i = 0; i < ah; ++i) hw += head_weights[i];
    hw /= (float)ah;
    if (o < 4096) {
        int d = o >> 6, a = o & 63;                       // Mtr[d][a] = M[a][d]
        float acc = 0.f;
        for (int j = 0; j < 64; ++j) acc += WQ[j*64 + a] * WK[j*64 + d];
        Mtr[o] = f2bf(acc * 0.125f);
    } else if (o < 8192) {
        int o2 = o - 4096;
        int j = o2 >> 6, b = o2 & 63;                     // Pbf[j][b]
        float acc = 0.f;
        for (int d = 0; d < 64; ++d) acc += Wout[j*64 + d] * WV[d*64 + b];
        Pbf[o2] = f2bf(acc * hw);
    }
}

__global__ __launch_bounds__(256, 3) void attn_kernel(
    const float* __restrict__ x_var, const float* __restrict__ x_clause,
    const int* __restrict__ cvar, const int* __restrict__ ccl,
    const float* __restrict__ sat, const unsigned short* __restrict__ Mtr,
    unsigned short* __restrict__ accum_bf, float* __restrict__ countv)
{
    __shared__ union {
        struct { unsigned short Zc[128 * XS]; unsigned short Xc[128 * XS]; } s; // 36864
        unsigned short attn[128 * AS];                                          // 34816
    } u;
    __shared__ unsigned short XcT[64 * AS];   // 17408; row pads hold ids(8B)+bias(4B)
    // total 54272 B -> 3 blocks/CU

    const int tid = threadIdx.x, lane = tid & 63, w = tid >> 6;
    const int c = blockIdx.x;
    const int m = lane & 31, hk = (lane >> 5) * 8;

    // M fragments straight from global (L1-resident, identical for all blocks)
    short8 mb0[4], mb1[4];
    #pragma unroll
    for (int ks = 0; ks < 4; ++ks) {
        mb0[ks] = *(const short8*)(Mtr + m * 64 + ks * 16 + hk);
        mb1[ks] = *(const short8*)(Mtr + (32 + m) * 64 + ks * 16 + hk);
    }

    // ---- gather: fp32 rows -> bf16 -> Xc (row-major) + XcT (transposed) ----
    {
        const int r = tid >> 1, half = tid & 1;
        int nid;
        const float* src;
        if (r < 64) {
            nid = cvar[c * 64 + r];
            src = x_var + (size_t)nid * 64;
        } else {
            int cid = ccl[c * 64 + (r - 64)];
            nid = NV + cid;
            src = x_clause + (size_t)cid * 64;
            if (half) *(float*)&XcT[(r - 64) * AS + 132] = sat[cid];  // GAMMA=1
        }
        if (!half) ((int*)&XcT[(r >> 1) * AS + 128])[r & 1] = nid;
        union { unsigned short us[32]; short8 v[4]; } hb;
        const float4* s4 = (const float4*)src + half * 8;
        #pragma unroll
        for (int i = 0; i < 8; ++i) {
            float4 v = s4[i];
            hb.us[i*4+0] = f2bf(v.x); hb.us[i*4+1] = f2bf(v.y);
            hb.us[i*4+2] = f2bf(v.z); hb.us[i*4+3] = f2bf(v.w);
        }
        const int c0 = half * 32;
        #pragma unroll
        for (int i = 0; i < 4; ++i) *(short8*)&u.s.Xc[r * XS + c0 + i * 8] = hb.v[i];
        #pragma unroll
        for (int i = 0; i < 32; ++i) XcT[(c0 + i) * AS + r] = hb.us[i];
    }
    __syncthreads();
    if (tid < 128)
        atomicAdd(&countv[((const int*)&XcT[(tid >> 1) * AS + 128])[tid & 1]], 1.0f);

    // ---- GEMM1: Zc = Xc @ M  (m-tile w, K=64; B from global regs) ----
    floatx16 z0 = {}, z1 = {};
    #pragma unroll
    for (int ks = 0; ks < 4; ++ks) {
        short8 a = *(const short8*)&u.s.Xc[(w * 32 + m) * XS + ks * 16 + hk];
        z0 = __builtin_amdgcn_mfma_f32_32x32x16_bf16(a, mb0[ks], z0, 0, 0, 0);
        z1 = __builtin_amdgcn_mfma_f32_32x32x16_bf16(a, mb1[ks], z1, 0, 0, 0);
    }
    #pragma unroll
    for (int r = 0; r < 16; ++r) {     // wave-local rows 32w..32w+31
        int row = w * 32 + crow(r, lane);
        u.s.Zc[row * XS + m]      = f2bf(z0[r]);
        u.s.Zc[row * XS + 32 + m] = f2bf(z1[r]);
    }

    // ---- GEMM2: scores = Zc @ Xc^T  (m-tile w, n-tiles 0..3, K=64) ----
    floatx16 sc[4] = {{}, {}, {}, {}};
    #pragma unroll
    for (int ks = 0; ks < 4; ++ks) {
        short8 a = *(const short8*)&u.s.Zc[(w * 32 + m) * XS + ks * 16 + hk];
        #pragma unroll
        for (int nt = 0; nt < 4; ++nt) {
            short8 b = *(const short8*)&u.s.Xc[(nt * 32 + m) * XS + ks * 16 + hk];
            sc[nt] = __builtin_amdgcn_mfma_f32_32x32x16_bf16(a, b, sc[nt], 0, 0, 0);
        }
    }

    // ---- bias + leaky_relu + exp (no max-sub: |score| <~ 8 << 88) ----
    const float b2 = *(const float*)&XcT[m * AS + 132];
    const float b3 = *(const float*)&XcT[(32 + m) * AS + 132];
    #pragma unroll
    for (int r = 0; r < 16; ++r) {
        float a0 = sc[0][r], a1 = sc[1][r], a2 = sc[2][r] + b2, a3 = sc[3][r] + b3;
        a0 = a0 > 0.f ? a0 : 0.2f * a0;
        a1 = a1 > 0.f ? a1 : 0.2f * a1;
        a2 = a2 > 0.f ? a2 : 0.2f * a2;
        a3 = a3 > 0.f ? a3 : 0.2f * a3;
        sc[0][r] = __expf(a0); sc[1][r] = __expf(a1);
        sc[2][r] = __expf(a2); sc[3][r] = __expf(a3);
    }

    __syncthreads();   // all waves done reading Zc/Xc before attn aliases them

    #pragma unroll
    for (int r = 0; r < 16; ++r) {
        int row = w * 32 + crow(r, lane);
        u.attn[row * AS + m]      = f2bf(sc[0][r]);
        u.attn[row * AS + 32 + m] = f2bf(sc[1][r]);
        u.attn[row * AS + 64 + m] = f2bf(sc[2][r]);
        u.attn[row * AS + 96 + m] = f2bf(sc[3][r]);
    }

    // ---- GEMM3: g = E@Xc (n-tiles 0..1) + rowsum = E@ones, K=128 ----
    const short8 vones = (short8)(short)0x3F80;   // bf16 1.0 splat
    floatx16 g0 = {}, g1 = {}, rs = {};
    #pragma unroll
    for (int ks = 0; ks < 8; ++ks) {
        short8 a  = *(const short8*)&u.attn[(w * 32 + m) * AS + ks * 16 + hk];
        short8 b0 = *(const short8*)&XcT[m * AS + ks * 16 + hk];
        short8 b1 = *(const short8*)&XcT[(32 + m) * AS + ks * 16 + hk];
        g0 = __builtin_amdgcn_mfma_f32_32x32x16_bf16(a, b0, g0, 0, 0, 0);
        g1 = __builtin_amdgcn_mfma_f32_32x32x16_bf16(a, b1, g1, 0, 0, 0);
        rs = __builtin_amdgcn_mfma_f32_32x32x16_bf16(a, vones, rs, 0, 0, 0);
    }

    // ---- normalize + pack adjacent cols (shfl_xor 1) + pk_add_bf16 scatter ----
    const bool ev = !(lane & 1);
    const int colbase = ev ? m : (31 + m);      // even: (m,m+1); odd: (31+m, 32+m)
    #pragma unroll
    for (int r = 0; r < 16; ++r) {
        int row = w * 32 + crow(r, lane);
        int nid = ((const int*)&XcT[(row >> 1) * AS + 128])[row & 1];
        float inv = __builtin_amdgcn_rcpf(rs[r]);
        float a0 = g0[r] * inv, a1 = g1[r] * inv;
        float t0 = __shfl_xor(a0, 1, 64);       // neighbor's col-m value
        float t1 = __shfl_xor(a1, 1, 64);       // neighbor's col-(32+m) value
        float lo = ev ? a0 : t1;
        float hi = ev ? t0 : a1;
        unsigned pk = (unsigned)f2bf(lo) | ((unsigned)f2bf(hi) << 16);
        unsigned long long addr =
            (unsigned long long)(accum_bf + (size_t)nid * 64 + colbase);
        asm volatile("global_atomic_pk_add_bf16 %0, %1, off"
                     :: "v"(addr), "v"(pk) : "memory");
    }
}

__global__ __launch_bounds__(256, 4) void finalize_kernel(
    const float* __restrict__ x_var, const float* __restrict__ x_clause,
    const unsigned short* __restrict__ accum_bf, const float* __restrict__ countv,
    const unsigned short* __restrict__ Pbf, const float* __restrict__ bout,
    float* __restrict__ out)
{
    __shared__ float cnts[256];
    const int tid = threadIdx.x, lane = tid & 63, w = tid >> 6;
    const int base = blockIdx.x * 256;
    {
        int n = base + tid;
        cnts[tid] = (n < NN) ? countv[n] : 1.f;
    }
    __syncthreads();

    const int m = lane & 31, hk = (lane >> 5) * 8;
    short8 pb[2][4];                              // P fragments via L1
    #pragma unroll
    for (int nt = 0; nt < 2; ++nt)
        #pragma unroll
        for (int ks = 0; ks < 4; ++ks)
            pb[nt][ks] = *(const short8*)(Pbf + (nt * 32 + m) * 64 + ks * 16 + hk);
    const float bias0 = bout[m], bias1 = bout[32 + m];

    #pragma unroll
    for (int tm = 0; tm < 2; ++tm) {
        int mt = w * 2 + tm;                      // rows base+mt*32 ..
        // A-fragments straight from global bf16 accum (divide deferred to epilogue)
        const unsigned short* arow = accum_bf + (size_t)(base + mt * 32 + m) * 64;
        floatx16 c0 = {}, c1 = {};
        #pragma unroll
        for (int ks = 0; ks < 4; ++ks) {
            short8 a = *(const short8*)(arow + ks * 16 + hk);
            c0 = __builtin_amdgcn_mfma_f32_32x32x16_bf16(a, pb[0][ks], c0, 0, 0, 0);
            c1 = __builtin_amdgcn_mfma_f32_32x32x16_bf16(a, pb[1][ks], c1, 0, 0, 0);
        }
        #pragma unroll
        for (int r = 0; r < 16; ++r) {
            int lrow = mt * 32 + crow(r, lane);
            int n = base + lrow;
            if (n < NN) {
                float inv = 1.0f / fmaxf(cnts[lrow], 1.0f);
                const float* xs = (n < NV) ? (x_var + (size_t)n * 64)
                                           : (x_clause + (size_t)(n - NV) * 64);
                out[(size_t)n * 64 + m]      = xs[m]      + c0[r] * inv + bias0;
                out[(size_t)n * 64 + 32 + m] = xs[32 + m] + c1[r] * inv + bias1;
            }
        }
    }
}

extern "C" void kernel_launch(void* const* d_in, const int* in_sizes, int n_in,
                              void* d_out, int out_size, void* d_ws, size_t ws_size,
                              hipStream_t stream)
{
    const float* x_var        = (const float*)d_in[0];
    const float* x_clause     = (const float*)d_in[1];
    const int*   cvar         = (const int*)d_in[4];
    const int*   ccl          = (const int*)d_in[5];
    const float* sat          = (const float*)d_in[6];
    const int*   active_heads = (const int*)d_in[7];
    const float* WQ           = (const float*)d_in[8];
    const float* WK           = (const float*)d_in[9];
    const float* WV           = (const float*)d_in[10];
    const float* head_weights = (const float*)d_in[11];
    const float* Wout         = (const float*)d_in[12];
    const float* bout         = (const float*)d_in[13];

    unsigned short* accum_bf = (unsigned short*)d_ws;          // NN*64 bf16
    float* countv = (float*)(accum_bf + (size_t)NN * 64);      // NN f32
    unsigned short* Mtr = (unsigned short*)(countv + NN);      // 4096 bf16
    unsigned short* Pbf = Mtr + 4096;                          // 4096 bf16

    hipMemsetAsync(accum_bf, 0, (size_t)NN * 64 * 2 + (size_t)NN * 4, stream);
    prep_kernel<<<32, 256, 0, stream>>>(WQ, WK, WV, Wout, head_weights, active_heads, Mtr, Pbf);
    attn_kernel<<<NCLUST, 256, 0, stream>>>(x_var, x_clause, cvar, ccl, sat, Mtr, accum_bf, countv);
    finalize_kernel<<<(NN + 255) / 256, 256, 0, stream>>>(x_var, x_clause, accum_bf, countv, Pbf, bout, (float*)d_out);
}

// Round 6
// 213.610 us; speedup vs baseline: 3.3697x; 1.0048x over previous
//
#include <hip/hip_runtime.h>

// IntraClusterGAT on MI355X — Round 6: occupancy push (4 blocks/CU).
//   prep:  Mtr = (WQ^T WK/8)^T, Pbf = hw*Wout@WV (bf16, in ws)
//   attn:  gather fp32->bf16 Xc (row-major only; XcT dropped) -> Zc=Xc@M (MFMA,
//          M frags from global/L1) -> scores=Zc@Xc^T (MFMA) -> exp -> rowsum via
//          shfl (fp32) -> scale -> E-half stores (alias Zc, wave-local) inter-
//          leaved with GEMM3 halves (B-frags via ds_read_u16 from row-major Xc)
//          -> pk_add_bf16 atomic scatter.  1 barrier/cluster.
//   final: out = x + (accum@P^T)/max(cnt,1) + b  (MFMA, A-frags from global)
//
// attn LDS = 37632B, launch_bounds(256,4), peak ~110 regs -> 4 blocks/CU.
// ws: accum_bf[NN*64] bf16 | countv[NN] f32 | Mtr 4096 bf16 | Pbf 4096 bf16

#define NV 100000
#define NN 200000
#define NCLUST 2048
#define XS 72    // Xc/Eh row stride (bf16): 144B, 16B-aligned

typedef __attribute__((ext_vector_type(8))) short short8;
typedef __attribute__((ext_vector_type(16))) float floatx16;

__device__ __forceinline__ unsigned short f2bf(float f) {
    union { float f; unsigned u; } v; v.f = f;
    unsigned r = v.u + 0x7fffu + ((v.u >> 16) & 1u);   // RNE
    return (unsigned short)(r >> 16);
}
__device__ __forceinline__ int crow(int r, int lane) {   // MFMA 32x32 C row map
    return (r & 3) + 8 * (r >> 2) + 4 * (lane >> 5);
}

__global__ __launch_bounds__(256) void prep_kernel(
    const float* __restrict__ WQ, const float* __restrict__ WK,
    const float* __restrict__ WV, const float* __restrict__ Wout,
    const float* __restrict__ head_weights, const int* __restrict__ active_heads_p,
    unsigned short* __restrict__ Mtr, unsigned short* __restrict__ Pbf)
{
    int o = blockIdx.x * blockDim.x + threadIdx.x;
    int ah = active_heads_p[0];
    float hw = 0.f;
    for (int i = 0; i < ah; ++i) hw += head_weights[i];
    hw /= (float)ah;
    if (o < 4096) {
        int d = o >> 6, a = o & 63;                       // Mtr[d][a] = M[a][d]
        float acc = 0.f;
        for (int j = 0; j < 64; ++j) acc += WQ[j*64 + a] * WK[j*64 + d];
        Mtr[o] = f2bf(acc * 0.125f);
    } else if (o < 8192) {
        int o2 = o - 4096;
        int j = o2 >> 6, b = o2 & 63;                     // Pbf[j][b]
        float acc = 0.f;
        for (int d = 0; d < 64; ++d) acc += Wout[j*64 + d] * WV[d*64 + b];
        Pbf[o2] = f2bf(acc * hw);
    }
}

__global__ __launch_bounds__(256, 4) void attn_kernel(
    const float* __restrict__ x_var, const float* __restrict__ x_clause,
    const int* __restrict__ cvar, const int* __restrict__ ccl,
    const float* __restrict__ sat, const unsigned short* __restrict__ Mtr,
    unsigned short* __restrict__ accum_bf, float* __restrict__ countv)
{
    __shared__ unsigned short Xc[128 * XS];   // 18432, persistent
    __shared__ unsigned short Eh[128 * XS];   // 18432, Zc then E-halves (wave-local rows)
    __shared__ int   ids[128];                //   512
    __shared__ float biascl[64];              //   256
    // total 37632 B -> 4 blocks/CU

    const int tid = threadIdx.x, lane = tid & 63, w = tid >> 6;
    const int c = blockIdx.x;
    const int m = lane & 31, hk = (lane >> 5) * 8;

    // ---- gather: fp32 rows -> bf16 -> Xc row-major only ----
    {
        const int r = tid >> 1, half = tid & 1;
        int nid;
        const float* src;
        if (r < 64) {
            nid = cvar[c * 64 + r];
            src = x_var + (size_t)nid * 64;
        } else {
            int cid = ccl[c * 64 + (r - 64)];
            nid = NV + cid;
            src = x_clause + (size_t)cid * 64;
            if (half) biascl[r - 64] = sat[cid];   // GAMMA = 1
        }
        if (!half) ids[r] = nid;
        union { unsigned short us[32]; short8 v[4]; } hb;
        const float4* s4 = (const float4*)src + half * 8;
        #pragma unroll
        for (int i = 0; i < 8; ++i) {
            float4 v = s4[i];
            hb.us[i*4+0] = f2bf(v.x); hb.us[i*4+1] = f2bf(v.y);
            hb.us[i*4+2] = f2bf(v.z); hb.us[i*4+3] = f2bf(v.w);
        }
        const int c0 = half * 32;
        #pragma unroll
        for (int i = 0; i < 4; ++i) *(short8*)&Xc[r * XS + c0 + i * 8] = hb.v[i];
    }
    __syncthreads();
    if (tid < 128) atomicAdd(&countv[ids[tid]], 1.0f);

    // ---- GEMM1: Zc = Xc @ M  (m-tile w, K=64; M frags from global/L1) ----
    {
        floatx16 z0 = {}, z1 = {};
        #pragma unroll
        for (int ks = 0; ks < 4; ++ks) {
            short8 mb0 = *(const short8*)(Mtr + m * 64 + ks * 16 + hk);
            short8 mb1 = *(const short8*)(Mtr + (32 + m) * 64 + ks * 16 + hk);
            short8 a = *(const short8*)&Xc[(w * 32 + m) * XS + ks * 16 + hk];
            z0 = __builtin_amdgcn_mfma_f32_32x32x16_bf16(a, mb0, z0, 0, 0, 0);
            z1 = __builtin_amdgcn_mfma_f32_32x32x16_bf16(a, mb1, z1, 0, 0, 0);
        }
        #pragma unroll
        for (int r = 0; r < 16; ++r) {     // wave-local rows 32w..32w+31
            int row = w * 32 + crow(r, lane);
            Eh[row * XS + m]      = f2bf(z0[r]);
            Eh[row * XS + 32 + m] = f2bf(z1[r]);
        }
    }

    // ---- GEMM2: scores = Zc @ Xc^T  (m-tile w, n-tiles 0..3, K=64) ----
    floatx16 sc[4] = {{}, {}, {}, {}};
    #pragma unroll
    for (int ks = 0; ks < 4; ++ks) {
        short8 a = *(const short8*)&Eh[(w * 32 + m) * XS + ks * 16 + hk];
        #pragma unroll
        for (int nt = 0; nt < 4; ++nt) {
            short8 b = *(const short8*)&Xc[(nt * 32 + m) * XS + ks * 16 + hk];
            sc[nt] = __builtin_amdgcn_mfma_f32_32x32x16_bf16(a, b, sc[nt], 0, 0, 0);
        }
    }

    // ---- bias + leaky_relu + exp + rowsum(shfl) + normalize (all fp32) ----
    const float b2 = biascl[m], b3 = biascl[32 + m];
    #pragma unroll
    for (int r = 0; r < 16; ++r) {
        float a0 = sc[0][r], a1 = sc[1][r], a2 = sc[2][r] + b2, a3 = sc[3][r] + b3;
        a0 = a0 > 0.f ? a0 : 0.2f * a0;
        a1 = a1 > 0.f ? a1 : 0.2f * a1;
        a2 = a2 > 0.f ? a2 : 0.2f * a2;
        a3 = a3 > 0.f ? a3 : 0.2f * a3;
        a0 = __expf(a0); a1 = __expf(a1); a2 = __expf(a2); a3 = __expf(a3);
        float s4 = (a0 + a1) + (a2 + a3);       // row's 32-col partial per lane
        #pragma unroll
        for (int off = 1; off < 32; off <<= 1) s4 += __shfl_xor(s4, off, 64);
        float inv = __builtin_amdgcn_rcpf(s4);  // full 128-col rowsum (half-wave)
        sc[0][r] = a0 * inv; sc[1][r] = a1 * inv;
        sc[2][r] = a2 * inv; sc[3][r] = a3 * inv;
    }

    // ---- E-half 1 (cols 0..63) over Zc rows (wave-local; in-order DS) ----
    #pragma unroll
    for (int r = 0; r < 16; ++r) {
        int row = w * 32 + crow(r, lane);
        Eh[row * XS + m]      = f2bf(sc[0][r]);
        Eh[row * XS + 32 + m] = f2bf(sc[1][r]);
    }

    // ---- GEMM3 half 1: t = 0..63 (B cols via ds_read_u16 from Xc) ----
    floatx16 g0 = {}, g1 = {};
    #pragma unroll
    for (int ks = 0; ks < 4; ++ks) {
        short8 a = *(const short8*)&Eh[(w * 32 + m) * XS + ks * 16 + hk];
        short8 b0, b1;
        #pragma unroll
        for (int j = 0; j < 8; ++j) {
            int t = ks * 16 + hk + j;
            b0[j] = (short)Xc[t * XS + m];
            b1[j] = (short)Xc[t * XS + 32 + m];
        }
        g0 = __builtin_amdgcn_mfma_f32_32x32x16_bf16(a, b0, g0, 0, 0, 0);
        g1 = __builtin_amdgcn_mfma_f32_32x32x16_bf16(a, b1, g1, 0, 0, 0);
    }

    // ---- E-half 2 (cols 64..127) ----
    #pragma unroll
    for (int r = 0; r < 16; ++r) {
        int row = w * 32 + crow(r, lane);
        Eh[row * XS + m]      = f2bf(sc[2][r]);
        Eh[row * XS + 32 + m] = f2bf(sc[3][r]);
    }

    // ---- GEMM3 half 2: t = 64..127 ----
    #pragma unroll
    for (int ks = 0; ks < 4; ++ks) {
        short8 a = *(const short8*)&Eh[(w * 32 + m) * XS + ks * 16 + hk];
        short8 b0, b1;
        #pragma unroll
        for (int j = 0; j < 8; ++j) {
            int t = 64 + ks * 16 + hk + j;
            b0[j] = (short)Xc[t * XS + m];
            b1[j] = (short)Xc[t * XS + 32 + m];
        }
        g0 = __builtin_amdgcn_mfma_f32_32x32x16_bf16(a, b0, g0, 0, 0, 0);
        g1 = __builtin_amdgcn_mfma_f32_32x32x16_bf16(a, b1, g1, 0, 0, 0);
    }

    // ---- pack adjacent cols (shfl_xor 1) + pk_add_bf16 scatter (pre-normalized) ----
    const bool ev = !(lane & 1);
    const int colbase = ev ? m : (31 + m);
    #pragma unroll
    for (int r = 0; r < 16; ++r) {
        int row = w * 32 + crow(r, lane);
        int nid = ids[row];
        float a0 = g0[r], a1 = g1[r];
        float t0 = __shfl_xor(a0, 1, 64);
        float t1 = __shfl_xor(a1, 1, 64);
        float lo = ev ? a0 : t1;
        float hi = ev ? t0 : a1;
        unsigned pk = (unsigned)f2bf(lo) | ((unsigned)f2bf(hi) << 16);
        unsigned long long addr =
            (unsigned long long)(accum_bf + (size_t)nid * 64 + colbase);
        asm volatile("global_atomic_pk_add_bf16 %0, %1, off"
                     :: "v"(addr), "v"(pk) : "memory");
    }
}

__global__ __launch_bounds__(256, 4) void finalize_kernel(
    const float* __restrict__ x_var, const float* __restrict__ x_clause,
    const unsigned short* __restrict__ accum_bf, const float* __restrict__ countv,
    const unsigned short* __restrict__ Pbf, const float* __restrict__ bout,
    float* __restrict__ out)
{
    __shared__ float cnts[256];
    const int tid = threadIdx.x, lane = tid & 63, w = tid >> 6;
    const int base = blockIdx.x * 256;
    {
        int n = base + tid;
        cnts[tid] = (n < NN) ? countv[n] : 1.f;
    }
    __syncthreads();

    const int m = lane & 31, hk = (lane >> 5) * 8;
    short8 pb[2][4];                              // P fragments via L1
    #pragma unroll
    for (int nt = 0; nt < 2; ++nt)
        #pragma unroll
        for (int ks = 0; ks < 4; ++ks)
            pb[nt][ks] = *(const short8*)(Pbf + (nt * 32 + m) * 64 + ks * 16 + hk);
    const float bias0 = bout[m], bias1 = bout[32 + m];

    #pragma unroll
    for (int tm = 0; tm < 2; ++tm) {
        int mt = w * 2 + tm;                      // rows base+mt*32 ..
        const unsigned short* arow = accum_bf + (size_t)(base + mt * 32 + m) * 64;
        floatx16 c0 = {}, c1 = {};
        #pragma unroll
        for (int ks = 0; ks < 4; ++ks) {
            short8 a = *(const short8*)(arow + ks * 16 + hk);
            c0 = __builtin_amdgcn_mfma_f32_32x32x16_bf16(a, pb[0][ks], c0, 0, 0, 0);
            c1 = __builtin_amdgcn_mfma_f32_32x32x16_bf16(a, pb[1][ks], c1, 0, 0, 0);
        }
        #pragma unroll
        for (int r = 0; r < 16; ++r) {
            int lrow = mt * 32 + crow(r, lane);
            int n = base + lrow;
            if (n < NN) {
                float inv = 1.0f / fmaxf(cnts[lrow], 1.0f);
                const float* xs = (n < NV) ? (x_var + (size_t)n * 64)
                                           : (x_clause + (size_t)(n - NV) * 64);
                out[(size_t)n * 64 + m]      = xs[m]      + c0[r] * inv + bias0;
                out[(size_t)n * 64 + 32 + m] = xs[32 + m] + c1[r] * inv + bias1;
            }
        }
    }
}

extern "C" void kernel_launch(void* const* d_in, const int* in_sizes, int n_in,
                              void* d_out, int out_size, void* d_ws, size_t ws_size,
                              hipStream_t stream)
{
    const float* x_var        = (const float*)d_in[0];
    const float* x_clause     = (const float*)d_in[1];
    const int*   cvar         = (const int*)d_in[4];
    const int*   ccl          = (const int*)d_in[5];
    const float* sat          = (const float*)d_in[6];
    const int*   active_heads = (const int*)d_in[7];
    const float* WQ           = (const float*)d_in[8];
    const float* WK           = (const float*)d_in[9];
    const float* WV           = (const float*)d_in[10];
    const float* head_weights = (const float*)d_in[11];
    const float* Wout         = (const float*)d_in[12];
    const float* bout         = (const float*)d_in[13];

    unsigned short* accum_bf = (unsigned short*)d_ws;          // NN*64 bf16
    float* countv = (float*)(accum_bf + (size_t)NN * 64);      // NN f32
    unsigned short* Mtr = (unsigned short*)(countv + NN);      // 4096 bf16
    unsigned short* Pbf = Mtr + 4096;                          // 4096 bf16

    hipMemsetAsync(accum_bf, 0, (size_t)NN * 64 * 2 + (size_t)NN * 4, stream);
    prep_kernel<<<32, 256, 0, stream>>>(WQ, WK, WV, Wout, head_weights, active_heads, Mtr, Pbf);
    attn_kernel<<<NCLUST, 256, 0, stream>>>(x_var, x_clause, cvar, ccl, sat, Mtr, accum_bf, countv);
    finalize_kernel<<<(NN + 255) / 256, 256, 0, stream>>>(x_var, x_clause, accum_bf, countv, Pbf, bout, (float*)d_out);
}